// Round 3
// baseline (485.588 us; speedup 1.0000x reference)
//
#include <hip/hip_runtime.h>
#include <math.h>

#define TMAX 1000000
#define BINW 4096
#define BINSHIFT 12
#define NBIN 245                   // ceil(TMAX / BINW)
#define PADN (NBIN * BINW)         // 1,003,520 buckets (tail beyond TMAX stays zero)
#define FIXSCALE 65536.0f
#define INV_FIXSCALE (1.0 / 65536.0)

// ---- workspace layout (byte offsets), hist pipeline ----
// scal   : double[2]              @ 0     [0]=sum(ev*x)  [1]=sum(ev*logS)
// done   : u32                    @ 16
// bintot : double[NBIN]           @ 64    (1960 B)
// hist   : u64[PADN]              @ 2048  (8,028,160 B)  (count<<48)|fix16(exp)
#define OFF_SCAL     0
#define OFF_DONE     16
#define OFF_BINTOT   64
#define OFF_HIST     2048
#define NEED_HIST    ((size_t)OFF_HIST + (size_t)PADN * 8)
// fallback (R1 pipeline) layout
#define FB_BINTOT    15744
#define FB_CEXCL     17792
#define FB_BEXP      31488
#define FB_BEV       (FB_BEXP + PADN * 4)
#define NEED_MIN     ((size_t)FB_BEV + PADN * 4)

__device__ __forceinline__ int clamp_tau(float t) {
    int tau = (int)t;
    if (tau < 0) tau = 0;
    if (tau >= TMAX) tau = TMAX - 1;
    return tau;
}

// ---------- Pass 1: one packed u64 memory-side atomic per element ----------
// Per element: hist[tau] += (ev<<48) | round(exp(x)*65536).
// Per-bin exp totals via LDS f32 partial sums (245 entries), one f64 atomic
// flush per bin per block. No payload, no reorder, no partial-line RMW.
__global__ __launch_bounds__(256) void k_hist(const float* __restrict__ x,
                                              const float* __restrict__ tgt,
                                              unsigned long long* __restrict__ hist,
                                              double* __restrict__ bintot,
                                              double* __restrict__ scal, int n) {
    __shared__ float bsum[NBIN];
    __shared__ double wpart[4];
    const int t = threadIdx.x;
    const int lane = t & 63;
    const int wv = t >> 6;
    for (int i = t; i < NBIN; i += 256) bsum[i] = 0.0f;
    __syncthreads();

    double evx = 0.0;
    const int nth = gridDim.x * 256;
    const int tid = blockIdx.x * 256 + t;
    const int ngroups = n >> 2;
    const float4* x4 = (const float4*)x;
    const float4* t4 = (const float4*)tgt;
    for (int g = tid; g < ngroups; g += nth) {
        float4 xv = x4[g];
        float4 ta = t4[2 * g];         // (t0,e0,t1,e1)
        float4 tb = t4[2 * g + 1];     // (t2,e2,t3,e3)
        float xs[4] = {xv.x, xv.y, xv.z, xv.w};
        float ts[4] = {ta.x, ta.z, tb.x, tb.z};
        float es[4] = {ta.y, ta.w, tb.y, tb.w};
#pragma unroll
        for (int j = 0; j < 4; ++j) {
            int tau = clamp_tau(ts[j]);
            float ex = __expf(xs[j]);
            unsigned fx = __float2uint_rn(ex * FIXSCALE);          // exp(5.8)*2^16 < 2^25, fits
            unsigned long long ev = (es[j] != 0.0f) ? 1ull : 0ull;
            atomicAdd(&hist[tau], (ev << 48) | (unsigned long long)fx);  // fire-and-forget
            // quantized value keeps bintot consistent with bucket fixed-point sums
            atomicAdd(&bsum[tau >> BINSHIFT], (float)fx * (1.0f / FIXSCALE));
            if (ev) evx += (double)xs[j];
        }
    }
    // tail (n not multiple of 4)
    const float2* tg2 = (const float2*)tgt;
    for (int idx = (ngroups << 2) + tid; idx < n; idx += nth) {
        float xv = x[idx];
        float2 te = tg2[idx];
        int tau = clamp_tau(te.x);
        float ex = __expf(xv);
        unsigned fx = __float2uint_rn(ex * FIXSCALE);
        unsigned long long ev = (te.y != 0.0f) ? 1ull : 0ull;
        atomicAdd(&hist[tau], (ev << 48) | (unsigned long long)fx);
        atomicAdd(&bsum[tau >> BINSHIFT], (float)fx * (1.0f / FIXSCALE));
        if (ev) evx += (double)xv;
    }
    __syncthreads();                       // bsum complete

    // flush per-bin partials (245 f64 atomics per block, to 245 distinct lines)
    for (int i = t; i < NBIN; i += 256) {
        float s = bsum[i];
        if (s != 0.0f) unsafeAtomicAdd(&bintot[i], (double)s);
    }

    // evx: wave reduce + single atomic per block
#pragma unroll
    for (int d = 32; d > 0; d >>= 1) {
        double u = __shfl_down(evx, d);
        if (lane + d < 64) evx += u;
    }
    if (lane == 0) wpart[wv] = evx;
    __syncthreads();
    if (t == 0) {
        double s = wpart[0] + wpart[1] + wpart[2] + wpart[3];
        unsafeAtomicAdd(&scal[0], s);
    }
}

// ---------- Pass 2: read 4096 buckets/block + shfl suffix + count*log + ticket ----------
__global__ __launch_bounds__(1024) void k_fused2(const unsigned long long* __restrict__ hist,
                                                 const double* __restrict__ bintot,
                                                 double* __restrict__ scal,
                                                 unsigned* __restrict__ done,
                                                 float* __restrict__ out, int n) {
    __shared__ double wsumA[16];
    __shared__ double wsum[16];
    __shared__ double bcast;
    const int b = blockIdx.x;
    const int t = threadIdx.x;
    const int lane = t & 63;
    const int wv = t >> 6;

    // my 4 buckets (32 B/thread, fully coalesced)
    const unsigned long long* hb = hist + (size_t)b * BINW + t * 4;
    unsigned long long h[4];
    h[0] = hb[0]; h[1] = hb[1]; h[2] = hb[2]; h[3] = hb[3];

    // cross-bin exclusive suffix: sum bintot[b+1..NBIN-1]
    double ce = 0.0;
    for (int idx = b + 1 + t; idx < NBIN; idx += 1024) ce += bintot[idx];
#pragma unroll
    for (int d = 32; d > 0; d >>= 1) {
        double u = __shfl_down(ce, d);
        if (lane + d < 64) ce += u;
    }
    if (lane == 0) wsumA[wv] = ce;
    __syncthreads();
    if (t == 0) {
        double s = 0.0;
        for (int w = 0; w < 16; ++w) s += wsumA[w];
        bcast = s;
    }
    __syncthreads();
    const double cexcl = bcast;

    // per-thread segment of 4 buckets; intra-wave suffix via shfl, cross-wave via LDS
    double vex[4];
    unsigned vcnt[4];
    double segtot = 0.0;
#pragma unroll
    for (int j = 0; j < 4; ++j) {
        vex[j] = (double)(h[j] & 0xFFFFFFFFFFFFull) * INV_FIXSCALE;
        vcnt[j] = (unsigned)(h[j] >> 48);
        segtot += vex[j];
    }
    double isuf = segtot;                       // inclusive suffix within wave
#pragma unroll
    for (int d = 1; d < 64; d <<= 1) {
        double u = __shfl_down(isuf, d);
        if (lane + d < 64) isuf += u;
    }
    if (lane == 0) wsum[wv] = isuf;             // wave total
    __syncthreads();
    double wexcl = 0.0;
    for (int w = wv + 1; w < 16; ++w) wexcl += wsum[w];

    double run = cexcl + wexcl + (isuf - segtot);   // S strictly after my 4 buckets
    double local = 0.0;
#pragma unroll
    for (int j = 3; j >= 0; --j) {
        run += vex[j];
        if (vcnt[j]) local += (double)vcnt[j] * log(run);
    }

    // block reduce local
#pragma unroll
    for (int d = 32; d > 0; d >>= 1) {
        double u = __shfl_down(local, d);
        if (lane + d < 64) local += u;
    }
    if (lane == 0) wsumA[wv] = local;
    __syncthreads();
    if (t == 0) {
        double s = 0.0;
        for (int w = 0; w < 16; ++w) s += wsumA[w];
        unsafeAtomicAdd(&scal[1], s);
        __threadfence();
        unsigned tk = atomicAdd(done, 1u);
        if (tk == NBIN - 1) {                   // last block: finalize
            double ld = unsafeAtomicAdd(&scal[1], 0.0);   // device-scope atomic read
            double loss = ld - scal[0];
            if (loss < 0.0) loss = 0.0;
            out[0] = (float)sqrt(loss / (double)n);
        }
    }
}

// ================= fallback path (small ws): R1 pipeline =================
__global__ void k_accum(const float* __restrict__ x, const float* __restrict__ tgt,
                        float* __restrict__ bexp, float* __restrict__ bev,
                        double* __restrict__ evx_out, int ngroups) {
    double local = 0.0;
    const int nt = gridDim.x * blockDim.x;
    const int tid = blockIdx.x * blockDim.x + threadIdx.x;
    const float4* x4 = (const float4*)x;
    const float4* t4 = (const float4*)tgt;
    for (int g = tid; g < ngroups; g += nt) {
        float4 xv = x4[g];
        float4 ta = t4[2 * g];
        float4 tb = t4[2 * g + 1];
        float xs[4] = {xv.x, xv.y, xv.z, xv.w};
        float ts[4] = {ta.x, ta.z, tb.x, tb.z};
        float es[4] = {ta.y, ta.w, tb.y, tb.w};
#pragma unroll
        for (int j = 0; j < 4; ++j) {
            int tau = clamp_tau(ts[j]);
            unsafeAtomicAdd(&bexp[tau], __expf(xs[j]));
            if (es[j] != 0.0f) unsafeAtomicAdd(&bev[tau], es[j]);
            local += (double)(es[j] * xs[j]);
        }
    }
    __shared__ double sm[256];
    sm[threadIdx.x] = local;
    __syncthreads();
    for (int s = 128; s > 0; s >>= 1) {
        if (threadIdx.x < s) sm[threadIdx.x] += sm[threadIdx.x + s];
        __syncthreads();
    }
    if (threadIdx.x == 0) atomicAdd(evx_out, sm[0]);
}

__global__ void k_chunksum(const float* __restrict__ bexp, double* __restrict__ bintot) {
    const int b = blockIdx.x;
    double local = 0.0;
    for (int i = b * BINW + (int)threadIdx.x; i < (b + 1) * BINW; i += (int)blockDim.x)
        local += (double)bexp[i];
    __shared__ double sm[256];
    sm[threadIdx.x] = local;
    __syncthreads();
    for (int s = 128; s > 0; s >>= 1) {
        if (threadIdx.x < s) sm[threadIdx.x] += sm[threadIdx.x + s];
        __syncthreads();
    }
    if (threadIdx.x == 0) bintot[b] = sm[0];
}

__global__ __launch_bounds__(256) void k_scanbins(const double* __restrict__ bintot,
                                                  double* __restrict__ cexcl) {
    __shared__ double sm[256];
    const int t = threadIdx.x;
    sm[t] = (t < NBIN) ? bintot[t] : 0.0;
    __syncthreads();
    for (int d = 1; d < 256; d <<= 1) {
        double v = (t + d < 256) ? sm[t + d] : 0.0;
        __syncthreads();
        sm[t] += v;
        __syncthreads();
    }
    double e = (t + 1 < 256) ? sm[t + 1] : 0.0;
    __syncthreads();
    cexcl[t] = e;
}

__global__ __launch_bounds__(256) void k_logdot_g(const float* __restrict__ bexp,
                                                  const float* __restrict__ bev,
                                                  const double* __restrict__ cexcl,
                                                  double* __restrict__ logdot) {
    const int b = blockIdx.x;
    const int t = threadIdx.x;
    const float4* e4 = (const float4*)(bexp + b * BINW + t * 16);
    const float4* v4 = (const float4*)(bev + b * BINW + t * 16);
    float ve[16], vv[16];
#pragma unroll
    for (int q = 0; q < 4; ++q) {
        float4 a = e4[q], bb = v4[q];
        ve[4 * q] = a.x; ve[4 * q + 1] = a.y; ve[4 * q + 2] = a.z; ve[4 * q + 3] = a.w;
        vv[4 * q] = bb.x; vv[4 * q + 1] = bb.y; vv[4 * q + 2] = bb.z; vv[4 * q + 3] = bb.w;
    }
    double segtot = 0.0;
#pragma unroll
    for (int j = 0; j < 16; ++j) segtot += (double)ve[j];
    __shared__ double sm[256];
    sm[t] = segtot;
    __syncthreads();
    for (int d = 1; d < 256; d <<= 1) {
        double v = (t + d < 256) ? sm[t + d] : 0.0;
        __syncthreads();
        sm[t] += v;
        __syncthreads();
    }
    double excl = (t < 255) ? sm[t + 1] : 0.0;
    double run = cexcl[b] + excl;
    double local = 0.0;
#pragma unroll
    for (int j = 15; j >= 0; --j) {
        run += (double)ve[j];
        if (vv[j] > 0.0f) local += (double)vv[j] * log(run);
    }
    __syncthreads();
    sm[t] = local;
    __syncthreads();
    for (int s = 128; s > 0; s >>= 1) {
        if (t < s) sm[t] += sm[t + s];
        __syncthreads();
    }
    if (t == 0) atomicAdd(logdot, sm[0]);
}

__global__ void k_final(const double* __restrict__ scal, float* __restrict__ out, int n) {
    if (threadIdx.x == 0 && blockIdx.x == 0) {
        double loss = scal[1] - scal[0];
        if (loss < 0.0) loss = 0.0;
        out[0] = (float)sqrt(loss / (double)n);
    }
}

extern "C" void kernel_launch(void* const* d_in, const int* in_sizes, int n_in,
                              void* d_out, int out_size, void* d_ws, size_t ws_size,
                              hipStream_t stream) {
    const float* x = (const float*)d_in[0];
    const float* tgt = (const float*)d_in[1];
    float* out = (float*)d_out;
    int n = in_sizes[0];
    char* ws = (char*)d_ws;

    if (ws_size >= NEED_HIST) {
        double* scal = (double*)(ws + OFF_SCAL);
        unsigned* done = (unsigned*)(ws + OFF_DONE);
        double* bintot = (double*)(ws + OFF_BINTOT);
        unsigned long long* hist = (unsigned long long*)(ws + OFF_HIST);
        hipMemsetAsync(ws, 0, NEED_HIST, stream);
        k_hist<<<1024, 256, 0, stream>>>(x, tgt, hist, bintot, scal, n);
        k_fused2<<<NBIN, 1024, 0, stream>>>(hist, bintot, scal, done, out, n);
    } else if (ws_size >= NEED_MIN) {
        double* scal = (double*)(ws + OFF_SCAL);
        float* bexp = (float*)(ws + FB_BEXP);
        float* bev = (float*)(ws + FB_BEV);
        double* bintotF = (double*)(ws + FB_BINTOT);
        double* cexclF = (double*)(ws + FB_CEXCL);
        hipMemsetAsync(ws, 0, NEED_MIN, stream);
        k_accum<<<2048, 256, 0, stream>>>(x, tgt, bexp, bev, scal, n / 4);
        k_chunksum<<<NBIN, 256, 0, stream>>>(bexp, bintotF);
        k_scanbins<<<1, 256, 0, stream>>>(bintotF, cexclF);
        k_logdot_g<<<NBIN, 256, 0, stream>>>(bexp, bev, cexclF, scal + 1);
        k_final<<<1, 1, 0, stream>>>(scal, out, n);
    }
}

// Round 4
// 174.583 us; speedup vs baseline: 2.7814x; 2.7814x over previous
//
#include <hip/hip_runtime.h>
#include <math.h>

#define TMAX 1000000
#define BINW 4096
#define BINSHIFT 12
#define NBIN 245                   // ceil(TMAX / BINW)
#define PADN (NBIN * BINW)
#define TILE 8192
#define NTHR 512
#define BT_STRIDE 8                // doubles: 64B per bin total line
#define FIXSCALE 65536.0f
#define INV_FIXSCALE (1.0 / 65536.0)

// ---- workspace layout (byte offsets), tile-major pipeline ----
// scal    : double[2]            @ 0      [0]=sum(ev*x)  [1]=sum(ev*logS)
// done    : u32                  @ 16
// bintot  : double[245*8]        @ 64     ends 15744 (64B-padded per bin)
// lptab   : u16[ntiles*256]      @ 15744  (512 B per tile: bin-prefix table)
// payload : u32[ntiles*TILE]     @ 15744 + ntiles*512  (tile-major, bin-sorted in tile)
#define OFF_SCAL     0
#define OFF_DONE     16
#define OFF_BINTOT   64
#define OFF_LPTAB    15744
#define MEMSET_BYTES 15744
// fallback (R1 pipeline) layout
#define FB_BINTOT    15744
#define FB_CEXCL     17792
#define FB_BEXP      31488
#define FB_BEV       (FB_BEXP + PADN * 4)
#define NEED_MIN     ((size_t)FB_BEV + PADN * 4)

__device__ __forceinline__ int clamp_tau(float t) {
    int tau = (int)t;
    if (tau < 0) tau = 0;
    if (tau >= TMAX) tau = TMAX - 1;
    return tau;
}

__device__ __forceinline__ unsigned enc_payload(float xv, float tv, float ev_f, int* bin_out) {
    int tau = clamp_tau(tv);
    *bin_out = tau >> BINSHIFT;
    int fine = tau & (BINW - 1);
    float ex = __expf(xv);
    unsigned bb = __float_as_uint(ex);
    bb = (bb + 0x7FFFu + ((bb >> 16) & 1u)) >> 16;     // bf16 RNE
    unsigned ev = (ev_f != 0.0f) ? 1u : 0u;
    return (bb << 16) | ((unsigned)fine << 1) | ev;
}

__device__ __forceinline__ float dec_exp(unsigned p) {
    return __uint_as_float((p >> 16) << 16);
}

__device__ __forceinline__ void hist1(unsigned long long* hist, unsigned p) {
    float ex = dec_exp(p);
    unsigned fx = __float2uint_rn(ex * FIXSCALE);
    unsigned long long add = ((unsigned long long)(p & 1u) << 48) | (unsigned long long)fx;
    atomicAdd(&hist[(p >> 1) & (BINW - 1)], add);
}

// ---------- Pass 1: per-tile bin sort, tile-major contiguous store ----------
// All global writes fully coalesced (uint4 payload block + 512B lptab burst).
// No cursor atomics, no binof2, no partial-line RMW, no CAP.
__global__ __launch_bounds__(NTHR, 8) void k_scat2(const float* __restrict__ x,
                                                   const float* __restrict__ tgt,
                                                   unsigned short* __restrict__ lptab,
                                                   unsigned* __restrict__ payload,
                                                   double* __restrict__ bintot,
                                                   double* __restrict__ evx_out, int n) {
    __shared__ unsigned cnt[256];          // per-bin rank counters
    __shared__ unsigned lpre[256];         // tile-local exclusive prefix (all 256 defined)
    __shared__ unsigned pay_lds[TILE];
    __shared__ unsigned wtot_s[8];
    __shared__ double wpart[8];
    const int t = threadIdx.x;
    const int lane = t & 63;
    const int wv = t >> 6;
    if (t < 256) cnt[t] = 0;
    __syncthreads();

    const int tile0 = blockIdx.x * TILE;
    const int tilecount = min(TILE, n - tile0);
    unsigned pay[16], meta[16];
    double evx = 0.0;

    if (tilecount == TILE) {
        const float4* x4 = (const float4*)x;
        const float4* t4 = (const float4*)tgt;
        const int g0 = blockIdx.x * (TILE / 4);
#pragma unroll
        for (int j = 0; j < 4; ++j) {
            const int g = g0 + j * NTHR + t;
            float4 xv = x4[g];
            float4 ta = t4[2 * g];         // (t0,e0,t1,e1)
            float4 tb = t4[2 * g + 1];     // (t2,e2,t3,e3)
            float xs[4] = {xv.x, xv.y, xv.z, xv.w};
            float ts[4] = {ta.x, ta.z, tb.x, tb.z};
            float es[4] = {ta.y, ta.w, tb.y, tb.w};
#pragma unroll
            for (int e = 0; e < 4; ++e) {
                int bin;
                unsigned p = enc_payload(xs[e], ts[e], es[e], &bin);
                unsigned r = atomicAdd(&cnt[bin], 1u);
                pay[4 * j + e] = p;
                meta[4 * j + e] = ((unsigned)bin << 13) | r;   // r < 8192
                if (p & 1) evx += (double)xs[e];
            }
        }
    } else {
        const float2* tg2 = (const float2*)tgt;
#pragma unroll
        for (int j = 0; j < 16; ++j) {
            int idx = tile0 + j * NTHR + t;
            if (idx < n) {
                float xv = x[idx];
                float2 te = tg2[idx];
                int bin;
                unsigned p = enc_payload(xv, te.x, te.y, &bin);
                unsigned r = atomicAdd(&cnt[bin], 1u);
                pay[j] = p;
                meta[j] = ((unsigned)bin << 13) | r;
                if (p & 1) evx += (double)xv;
            } else {
                meta[j] = 0xFFFFFFFFu;
            }
        }
    }
    __syncthreads();                       // (A) all ranks done

    // exclusive prefix over 256 bin counts: wave-shuffle scan (waves 0..3 carry data)
    const unsigned c = (t < 256) ? cnt[t] : 0u;
    unsigned pfx = c;
#pragma unroll
    for (int d = 1; d < 64; d <<= 1) {
        unsigned u = __shfl_up(pfx, d);
        if (lane >= d) pfx += u;
    }
    if (lane == 63) wtot_s[wv] = pfx;
    __syncthreads();                       // (B) wtot ready; all cnt reads complete
    unsigned wbase = 0;
    if (t < 256) {
        for (int w = 0; w < wv; ++w) wbase += wtot_s[w];
    }
    const unsigned excl = (t < 256) ? (wbase + pfx - c) : 0u;
    if (t < 256) {
        lpre[t] = excl;                    // defined for ALL t<256 (incl. empty bins)
        // prefix table out: entries >=245 equal tile total (empty high bins)
        lptab[(size_t)blockIdx.x * 256 + t] = (unsigned short)excl;
    }
    __syncthreads();                       // (C) lpre ready

    // scatter payloads into LDS ordered by (bin, rank)
#pragma unroll
    for (int j = 0; j < 16; ++j) {
        if (meta[j] != 0xFFFFFFFFu) {
            unsigned bin = meta[j] >> 13;
            pay_lds[lpre[bin] + (meta[j] & 0x1FFFu)] = pay[j];
        }
    }
    __syncthreads();                       // (D) pay_lds ready

    // per-bin exp totals from reordered LDS (registers excl/c)
    if (t < NBIN && c) {
        float s = 0.0f;
        for (unsigned k = excl; k < excl + c; ++k) s += dec_exp(pay_lds[k]);
        unsafeAtomicAdd(&bintot[t * BT_STRIDE], (double)s);
    }

    // tile-major contiguous store-out: fully coalesced uint4
    if (tilecount == TILE) {
        const uint4* s4 = (const uint4*)pay_lds;
        uint4* d4 = (uint4*)(payload + (size_t)blockIdx.x * TILE);
#pragma unroll
        for (int j = 0; j < 4; ++j) d4[j * NTHR + t] = s4[j * NTHR + t];
    } else {
        for (int k = t; k < tilecount; k += NTHR)
            payload[(size_t)blockIdx.x * TILE + k] = pay_lds[k];
    }

    // evx: wave-shuffle reduce, then single-thread combine
#pragma unroll
    for (int d = 32; d > 0; d >>= 1) {
        double u = __shfl_down(evx, d);
        if (lane + d < 64) evx += u;
    }
    if (lane == 0) wpart[wv] = evx;
    __syncthreads();
    if (t == 0) {
        double s = 0.0;
        for (int w = 0; w < 8; ++w) s += wpart[w];
        atomicAdd(evx_out, s);
    }
}

// ---------- Pass 2: per-bin gather across tiles + hist + suffix + count*log ----------
__global__ __launch_bounds__(1024) void k_gather(const unsigned* __restrict__ payload,
                                                 const unsigned short* __restrict__ lptab,
                                                 const double* __restrict__ bintot,
                                                 double* __restrict__ scal,
                                                 unsigned* __restrict__ done,
                                                 float* __restrict__ out, int n, int ntiles) {
    __shared__ unsigned long long hist[BINW];   // 32 KB: (ev_count<<48) | fixpoint_exp_sum
    __shared__ double wsumA[16];
    __shared__ double wsum[16];
    __shared__ double bcast;
    const int b = blockIdx.x;
    const int t = threadIdx.x;
    const int lane = t & 63;
    const int wv = t >> 6;

#pragma unroll
    for (int j = 0; j < BINW / 1024; ++j) hist[t + j * 1024] = 0ull;
    __syncthreads();

    // gather my bin's run from each tile; 16 waves, two runs in flight per wave
    for (int tau = wv; tau < ntiles; tau += 32) {
        const int tau2 = tau + 16;
        const unsigned short* lp0 = lptab + (size_t)tau * 256 + b;
        unsigned s0 = lp0[0], e0 = lp0[1];
        unsigned s1 = 0, e1 = 0;
        const bool have2 = (tau2 < ntiles);
        if (have2) {
            const unsigned short* lp1 = lptab + (size_t)tau2 * 256 + b;
            s1 = lp1[0]; e1 = lp1[1];
        }
        const unsigned k0 = s0 + lane, k1 = s1 + lane;
        const bool v0 = (k0 < e0);
        const bool v1 = have2 && (k1 < e1);
        unsigned p0 = 0, p1 = 0;
        if (v0) p0 = payload[(size_t)tau * TILE + k0];
        if (v1) p1 = payload[(size_t)tau2 * TILE + k1];
        if (v0) hist1(hist, p0);
        if (v1) hist1(hist, p1);
        for (unsigned k = k0 + 64; k < e0; k += 64)          // rare: run > 64
            hist1(hist, payload[(size_t)tau * TILE + k]);
        if (have2)
            for (unsigned k = k1 + 64; k < e1; k += 64)
                hist1(hist, payload[(size_t)tau2 * TILE + k]);
    }
    __syncthreads();

    // cross-bin exclusive suffix: sum bintot[b+1..NBIN-1]
    double ce = 0.0;
    for (int idx = b + 1 + t; idx < NBIN; idx += 1024) ce += bintot[idx * BT_STRIDE];
#pragma unroll
    for (int d = 32; d > 0; d >>= 1) {
        double u = __shfl_down(ce, d);
        if (lane + d < 64) ce += u;
    }
    if (lane == 0) wsumA[wv] = ce;
    __syncthreads();
    if (t == 0) {
        double s = 0.0;
        for (int w = 0; w < 16; ++w) s += wsumA[w];
        bcast = s;
    }
    __syncthreads();
    const double cexcl = bcast;

    // per-thread segment of 4 buckets; intra-wave suffix via shfl, cross-wave via LDS
    const int tb = t * 4;
    double vex[4];
    unsigned vcnt[4];
    double segtot = 0.0;
#pragma unroll
    for (int j = 0; j < 4; ++j) {
        unsigned long long h = hist[tb + j];
        vex[j] = (double)(h & 0xFFFFFFFFFFFFull) * INV_FIXSCALE;
        vcnt[j] = (unsigned)(h >> 48);
        segtot += vex[j];
    }
    double isuf = segtot;                       // inclusive suffix within wave
#pragma unroll
    for (int d = 1; d < 64; d <<= 1) {
        double u = __shfl_down(isuf, d);
        if (lane + d < 64) isuf += u;
    }
    if (lane == 0) wsum[wv] = isuf;             // wave total
    __syncthreads();
    double wexcl = 0.0;
    for (int w = wv + 1; w < 16; ++w) wexcl += wsum[w];

    double run = cexcl + wexcl + (isuf - segtot);   // S strictly after my 4 buckets
    double local = 0.0;
#pragma unroll
    for (int j = 3; j >= 0; --j) {
        run += vex[j];
        if (vcnt[j]) local += (double)vcnt[j] * log(run);
    }

    // block reduce local
#pragma unroll
    for (int d = 32; d > 0; d >>= 1) {
        double u = __shfl_down(local, d);
        if (lane + d < 64) local += u;
    }
    if (lane == 0) wsumA[wv] = local;
    __syncthreads();
    if (t == 0) {
        double s = 0.0;
        for (int w = 0; w < 16; ++w) s += wsumA[w];
        unsafeAtomicAdd(&scal[1], s);
        __threadfence();
        unsigned tk = atomicAdd(done, 1u);
        if (tk == NBIN - 1) {                   // last block: finalize
            double ld = unsafeAtomicAdd(&scal[1], 0.0);   // device-scope atomic read
            double loss = ld - scal[0];
            if (loss < 0.0) loss = 0.0;
            out[0] = (float)sqrt(loss / (double)n);
        }
    }
}

// ================= fallback path (small ws): R1 pipeline =================
__global__ void k_accum(const float* __restrict__ x, const float* __restrict__ tgt,
                        float* __restrict__ bexp, float* __restrict__ bev,
                        double* __restrict__ evx_out, int ngroups) {
    double local = 0.0;
    const int nt = gridDim.x * blockDim.x;
    const int tid = blockIdx.x * blockDim.x + threadIdx.x;
    const float4* x4 = (const float4*)x;
    const float4* t4 = (const float4*)tgt;
    for (int g = tid; g < ngroups; g += nt) {
        float4 xv = x4[g];
        float4 ta = t4[2 * g];
        float4 tb = t4[2 * g + 1];
        float xs[4] = {xv.x, xv.y, xv.z, xv.w};
        float ts[4] = {ta.x, ta.z, tb.x, tb.z};
        float es[4] = {ta.y, ta.w, tb.y, tb.w};
#pragma unroll
        for (int j = 0; j < 4; ++j) {
            int tau = clamp_tau(ts[j]);
            unsafeAtomicAdd(&bexp[tau], __expf(xs[j]));
            if (es[j] != 0.0f) unsafeAtomicAdd(&bev[tau], es[j]);
            local += (double)(es[j] * xs[j]);
        }
    }
    __shared__ double sm[256];
    sm[threadIdx.x] = local;
    __syncthreads();
    for (int s = 128; s > 0; s >>= 1) {
        if (threadIdx.x < s) sm[threadIdx.x] += sm[threadIdx.x + s];
        __syncthreads();
    }
    if (threadIdx.x == 0) atomicAdd(evx_out, sm[0]);
}

__global__ void k_chunksum(const float* __restrict__ bexp, double* __restrict__ bintot) {
    const int b = blockIdx.x;
    double local = 0.0;
    for (int i = b * BINW + (int)threadIdx.x; i < (b + 1) * BINW; i += (int)blockDim.x)
        local += (double)bexp[i];
    __shared__ double sm[256];
    sm[threadIdx.x] = local;
    __syncthreads();
    for (int s = 128; s > 0; s >>= 1) {
        if (threadIdx.x < s) sm[threadIdx.x] += sm[threadIdx.x + s];
        __syncthreads();
    }
    if (threadIdx.x == 0) bintot[b] = sm[0];
}

__global__ __launch_bounds__(256) void k_scanbins(const double* __restrict__ bintot,
                                                  double* __restrict__ cexcl) {
    __shared__ double sm[256];
    const int t = threadIdx.x;
    sm[t] = (t < NBIN) ? bintot[t] : 0.0;
    __syncthreads();
    for (int d = 1; d < 256; d <<= 1) {
        double v = (t + d < 256) ? sm[t + d] : 0.0;
        __syncthreads();
        sm[t] += v;
        __syncthreads();
    }
    double e = (t + 1 < 256) ? sm[t + 1] : 0.0;
    __syncthreads();
    cexcl[t] = e;
}

__global__ __launch_bounds__(256) void k_logdot_g(const float* __restrict__ bexp,
                                                  const float* __restrict__ bev,
                                                  const double* __restrict__ cexcl,
                                                  double* __restrict__ logdot) {
    const int b = blockIdx.x;
    const int t = threadIdx.x;
    const float4* e4 = (const float4*)(bexp + b * BINW + t * 16);
    const float4* v4 = (const float4*)(bev + b * BINW + t * 16);
    float ve[16], vv[16];
#pragma unroll
    for (int q = 0; q < 4; ++q) {
        float4 a = e4[q], bb = v4[q];
        ve[4 * q] = a.x; ve[4 * q + 1] = a.y; ve[4 * q + 2] = a.z; ve[4 * q + 3] = a.w;
        vv[4 * q] = bb.x; vv[4 * q + 1] = bb.y; vv[4 * q + 2] = bb.z; vv[4 * q + 3] = bb.w;
    }
    double segtot = 0.0;
#pragma unroll
    for (int j = 0; j < 16; ++j) segtot += (double)ve[j];
    __shared__ double sm[256];
    sm[t] = segtot;
    __syncthreads();
    for (int d = 1; d < 256; d <<= 1) {
        double v = (t + d < 256) ? sm[t + d] : 0.0;
        __syncthreads();
        sm[t] += v;
        __syncthreads();
    }
    double excl = (t < 255) ? sm[t + 1] : 0.0;
    double run = cexcl[b] + excl;
    double local = 0.0;
#pragma unroll
    for (int j = 15; j >= 0; --j) {
        run += (double)ve[j];
        if (vv[j] > 0.0f) local += (double)vv[j] * log(run);
    }
    __syncthreads();
    sm[t] = local;
    __syncthreads();
    for (int s = 128; s > 0; s >>= 1) {
        if (t < s) sm[t] += sm[t + s];
        __syncthreads();
    }
    if (t == 0) atomicAdd(logdot, sm[0]);
}

__global__ void k_final(const double* __restrict__ scal, float* __restrict__ out, int n) {
    if (threadIdx.x == 0 && blockIdx.x == 0) {
        double loss = scal[1] - scal[0];
        if (loss < 0.0) loss = 0.0;
        out[0] = (float)sqrt(loss / (double)n);
    }
}

extern "C" void kernel_launch(void* const* d_in, const int* in_sizes, int n_in,
                              void* d_out, int out_size, void* d_ws, size_t ws_size,
                              hipStream_t stream) {
    const float* x = (const float*)d_in[0];
    const float* tgt = (const float*)d_in[1];
    float* out = (float*)d_out;
    int n = in_sizes[0];
    char* ws = (char*)d_ws;

    const size_t ntiles = (size_t)(n + TILE - 1) / TILE;
    const size_t off_pay = (size_t)OFF_LPTAB + ntiles * 512;        // 64B-aligned
    const size_t need2 = off_pay + ntiles * (size_t)TILE * 4;

    if (ws_size >= need2 && n >= 4) {
        double* scal = (double*)(ws + OFF_SCAL);
        unsigned* done = (unsigned*)(ws + OFF_DONE);
        double* bintot = (double*)(ws + OFF_BINTOT);
        unsigned short* lptab = (unsigned short*)(ws + OFF_LPTAB);
        unsigned* payload = (unsigned*)(ws + off_pay);
        hipMemsetAsync(ws, 0, MEMSET_BYTES, stream);
        k_scat2<<<(int)ntiles, NTHR, 0, stream>>>(x, tgt, lptab, payload, bintot, scal, n);
        k_gather<<<NBIN, 1024, 0, stream>>>(payload, lptab, bintot, scal, done, out, n,
                                            (int)ntiles);
    } else if (ws_size >= NEED_MIN) {
        double* scal = (double*)(ws + OFF_SCAL);
        float* bexp = (float*)(ws + FB_BEXP);
        float* bev = (float*)(ws + FB_BEV);
        double* bintotF = (double*)(ws + FB_BINTOT);
        double* cexclF = (double*)(ws + FB_CEXCL);
        hipMemsetAsync(ws, 0, NEED_MIN, stream);
        k_accum<<<2048, 256, 0, stream>>>(x, tgt, bexp, bev, scal, n / 4);
        k_chunksum<<<NBIN, 256, 0, stream>>>(bexp, bintotF);
        k_scanbins<<<1, 256, 0, stream>>>(bintotF, cexclF);
        k_logdot_g<<<NBIN, 256, 0, stream>>>(bexp, bev, cexclF, scal + 1);
        k_final<<<1, 1, 0, stream>>>(scal, out, n);
    }
}

// Round 5
// 163.620 us; speedup vs baseline: 2.9678x; 1.0670x over previous
//
#include <hip/hip_runtime.h>
#include <math.h>

#define TMAX 1000000
#define BINW 4096
#define BINSHIFT 12
#define NBIN 245                   // ceil(TMAX / BINW)
#define PADN (NBIN * BINW)
#define TILE 8192
#define NTHR 512
#define BT_STRIDE 8                // doubles: 64B per bin total line
#define FIXSCALE 65536.0f
#define INV_FIXSCALE (1.0 / 65536.0)
#define SE_CHUNK 2048              // tiles of (start,end) prefetched per LDS chunk

// ---- workspace layout (byte offsets), tile-major pipeline ----
// scal    : double[2]            @ 0      [0]=sum(ev*x)  [1]=sum(ev*logS)
// done    : u32                  @ 16
// bintot  : double[245*8]        @ 64     ends 15744 (64B-padded per bin)
// lptab   : u16[ntiles*256]      @ 15744  (512 B per tile: bin-prefix table)
// payload : u32[ntiles*TILE]     @ 15744 + ntiles*512  (tile-major, bin-sorted in tile)
#define OFF_SCAL     0
#define OFF_DONE     16
#define OFF_BINTOT   64
#define OFF_LPTAB    15744
#define MEMSET_BYTES 15744
// fallback (R1 pipeline) layout
#define FB_BINTOT    15744
#define FB_CEXCL     17792
#define FB_BEXP      31488
#define FB_BEV       (FB_BEXP + PADN * 4)
#define NEED_MIN     ((size_t)FB_BEV + PADN * 4)

__device__ __forceinline__ int clamp_tau(float t) {
    int tau = (int)t;
    if (tau < 0) tau = 0;
    if (tau >= TMAX) tau = TMAX - 1;
    return tau;
}

__device__ __forceinline__ unsigned enc_payload(float xv, float tv, float ev_f, int* bin_out) {
    int tau = clamp_tau(tv);
    *bin_out = tau >> BINSHIFT;
    int fine = tau & (BINW - 1);
    float ex = __expf(xv);
    unsigned bb = __float_as_uint(ex);
    bb = (bb + 0x7FFFu + ((bb >> 16) & 1u)) >> 16;     // bf16 RNE
    unsigned ev = (ev_f != 0.0f) ? 1u : 0u;
    return (bb << 16) | ((unsigned)fine << 1) | ev;
}

__device__ __forceinline__ float dec_exp(unsigned p) {
    return __uint_as_float((p >> 16) << 16);
}

__device__ __forceinline__ void hist1(unsigned long long* hist, unsigned p) {
    float ex = dec_exp(p);
    unsigned fx = __float2uint_rn(ex * FIXSCALE);
    unsigned long long add = ((unsigned long long)(p & 1u) << 48) | (unsigned long long)fx;
    atomicAdd(&hist[(p >> 1) & (BINW - 1)], add);
}

// ---------- Pass 1: per-tile bin sort, tile-major contiguous store ----------
__global__ __launch_bounds__(NTHR, 8) void k_scat2(const float* __restrict__ x,
                                                   const float* __restrict__ tgt,
                                                   unsigned short* __restrict__ lptab,
                                                   unsigned* __restrict__ payload,
                                                   double* __restrict__ bintot,
                                                   double* __restrict__ evx_out, int n) {
    __shared__ unsigned cnt[256];          // per-bin rank counters
    __shared__ unsigned lpre[256];         // tile-local exclusive prefix (all 256 defined)
    __shared__ unsigned pay_lds[TILE];
    __shared__ unsigned wtot_s[8];
    __shared__ double wpart[8];
    const int t = threadIdx.x;
    const int lane = t & 63;
    const int wv = t >> 6;
    if (t < 256) cnt[t] = 0;
    __syncthreads();

    const int tile0 = blockIdx.x * TILE;
    const int tilecount = min(TILE, n - tile0);
    unsigned pay[16], meta[16];
    double evx = 0.0;

    if (tilecount == TILE) {
        const float4* x4 = (const float4*)x;
        const float4* t4 = (const float4*)tgt;
        const int g0 = blockIdx.x * (TILE / 4);
#pragma unroll
        for (int j = 0; j < 4; ++j) {
            const int g = g0 + j * NTHR + t;
            float4 xv = x4[g];
            float4 ta = t4[2 * g];         // (t0,e0,t1,e1)
            float4 tb = t4[2 * g + 1];     // (t2,e2,t3,e3)
            float xs[4] = {xv.x, xv.y, xv.z, xv.w};
            float ts[4] = {ta.x, ta.z, tb.x, tb.z};
            float es[4] = {ta.y, ta.w, tb.y, tb.w};
#pragma unroll
            for (int e = 0; e < 4; ++e) {
                int bin;
                unsigned p = enc_payload(xs[e], ts[e], es[e], &bin);
                unsigned r = atomicAdd(&cnt[bin], 1u);
                pay[4 * j + e] = p;
                meta[4 * j + e] = ((unsigned)bin << 13) | r;   // r < 8192
                if (p & 1) evx += (double)xs[e];
            }
        }
    } else {
        const float2* tg2 = (const float2*)tgt;
#pragma unroll
        for (int j = 0; j < 16; ++j) {
            int idx = tile0 + j * NTHR + t;
            if (idx < n) {
                float xv = x[idx];
                float2 te = tg2[idx];
                int bin;
                unsigned p = enc_payload(xv, te.x, te.y, &bin);
                unsigned r = atomicAdd(&cnt[bin], 1u);
                pay[j] = p;
                meta[j] = ((unsigned)bin << 13) | r;
                if (p & 1) evx += (double)xv;
            } else {
                meta[j] = 0xFFFFFFFFu;
            }
        }
    }
    __syncthreads();                       // (A) all ranks done

    // exclusive prefix over 256 bin counts: wave-shuffle scan (waves 0..3 carry data)
    const unsigned c = (t < 256) ? cnt[t] : 0u;
    unsigned pfx = c;
#pragma unroll
    for (int d = 1; d < 64; d <<= 1) {
        unsigned u = __shfl_up(pfx, d);
        if (lane >= d) pfx += u;
    }
    if (lane == 63) wtot_s[wv] = pfx;
    __syncthreads();                       // (B) wtot ready; all cnt reads complete
    unsigned wbase = 0;
    if (t < 256) {
        for (int w = 0; w < wv; ++w) wbase += wtot_s[w];
    }
    const unsigned excl = (t < 256) ? (wbase + pfx - c) : 0u;
    if (t < 256) {
        lpre[t] = excl;                    // defined for ALL t<256 (incl. empty bins)
        // prefix table out: entries >=245 equal tile total (empty high bins)
        lptab[(size_t)blockIdx.x * 256 + t] = (unsigned short)excl;
    }
    __syncthreads();                       // (C) lpre ready

    // scatter payloads into LDS ordered by (bin, rank)
#pragma unroll
    for (int j = 0; j < 16; ++j) {
        if (meta[j] != 0xFFFFFFFFu) {
            unsigned bin = meta[j] >> 13;
            pay_lds[lpre[bin] + (meta[j] & 0x1FFFu)] = pay[j];
        }
    }
    __syncthreads();                       // (D) pay_lds ready

    // per-bin exp totals from reordered LDS (registers excl/c)
    if (t < NBIN && c) {
        float s = 0.0f;
        for (unsigned k = excl; k < excl + c; ++k) s += dec_exp(pay_lds[k]);
        unsafeAtomicAdd(&bintot[t * BT_STRIDE], (double)s);
    }

    // tile-major contiguous store-out: fully coalesced uint4
    if (tilecount == TILE) {
        const uint4* s4 = (const uint4*)pay_lds;
        uint4* d4 = (uint4*)(payload + (size_t)blockIdx.x * TILE);
#pragma unroll
        for (int j = 0; j < 4; ++j) d4[j * NTHR + t] = s4[j * NTHR + t];
    } else {
        for (int k = t; k < tilecount; k += NTHR)
            payload[(size_t)blockIdx.x * TILE + k] = pay_lds[k];
    }

    // evx: wave-shuffle reduce, then single-thread combine
#pragma unroll
    for (int d = 32; d > 0; d >>= 1) {
        double u = __shfl_down(evx, d);
        if (lane + d < 64) evx += u;
    }
    if (lane == 0) wpart[wv] = evx;
    __syncthreads();
    if (t == 0) {
        double s = 0.0;
        for (int w = 0; w < 8; ++w) s += wpart[w];
        atomicAdd(evx_out, s);
    }
}

// ---------- Pass 2: per-bin gather across tiles + hist + suffix + count*log ----------
// R5: (1) prefetch the bin's (start,end) lptab column into LDS once (kills the
// per-iteration lptab->payload dependent chain); (2) 4 tiles in flight per wave.
__global__ __launch_bounds__(1024) void k_gather(const unsigned* __restrict__ payload,
                                                 const unsigned short* __restrict__ lptab,
                                                 const double* __restrict__ bintot,
                                                 double* __restrict__ scal,
                                                 unsigned* __restrict__ done,
                                                 float* __restrict__ out, int n, int ntiles) {
    __shared__ unsigned long long hist[BINW];   // 32 KB: (ev_count<<48) | fixpoint_exp_sum
    __shared__ unsigned serun[SE_CHUNK];        // 8 KB: (end<<16)|start per tile in chunk
    __shared__ double wsumA[16];
    __shared__ double wsum[16];
    __shared__ double bcast;
    const int b = blockIdx.x;
    const int t = threadIdx.x;
    const int lane = t & 63;
    const int wv = t >> 6;

#pragma unroll
    for (int j = 0; j < BINW / 1024; ++j) hist[t + j * 1024] = 0ull;
    __syncthreads();

    for (int chunk = 0; chunk < ntiles; chunk += SE_CHUNK) {
        const int m = min(SE_CHUNK, ntiles - chunk);
        // prefetch (start,end) for this chunk: one u16-pair load per tile (b<=244<255)
        for (int i = t; i < m; i += 1024) {
            const unsigned short* lp = lptab + ((size_t)(chunk + i) << 8) + b;
            serun[i] = ((unsigned)lp[1] << 16) | (unsigned)lp[0];
        }
        __syncthreads();

        // each wave: 4 tiles in flight per iteration
        for (int base = wv * 4; base < m; base += 64) {
            unsigned sa[4], ea[4], pv[4];
            bool v[4];
#pragma unroll
            for (int u = 0; u < 4; ++u) {
                const int i = base + u;
                const unsigned se = (i < m) ? serun[i] : 0u;
                sa[u] = se & 0xFFFFu;
                ea[u] = se >> 16;
                const unsigned k = sa[u] + lane;
                v[u] = (i < m) && (k < ea[u]);
                if (v[u]) pv[u] = payload[(size_t)(chunk + i) * TILE + k];
            }
#pragma unroll
            for (int u = 0; u < 4; ++u)
                if (v[u]) hist1(hist, pv[u]);
            // rare: run longer than 64
#pragma unroll
            for (int u = 0; u < 4; ++u) {
                const int i = base + u;
                if (i < m) {
                    for (unsigned k = sa[u] + lane + 64; k < ea[u]; k += 64)
                        hist1(hist, payload[(size_t)(chunk + i) * TILE + k]);
                }
            }
        }
        __syncthreads();                   // serun reuse safe for next chunk
    }
    __syncthreads();

    // cross-bin exclusive suffix: sum bintot[b+1..NBIN-1]
    double ce = 0.0;
    for (int idx = b + 1 + t; idx < NBIN; idx += 1024) ce += bintot[idx * BT_STRIDE];
#pragma unroll
    for (int d = 32; d > 0; d >>= 1) {
        double u = __shfl_down(ce, d);
        if (lane + d < 64) ce += u;
    }
    if (lane == 0) wsumA[wv] = ce;
    __syncthreads();
    if (t == 0) {
        double s = 0.0;
        for (int w = 0; w < 16; ++w) s += wsumA[w];
        bcast = s;
    }
    __syncthreads();
    const double cexcl = bcast;

    // per-thread segment of 4 buckets; intra-wave suffix via shfl, cross-wave via LDS
    const int tb = t * 4;
    double vex[4];
    unsigned vcnt[4];
    double segtot = 0.0;
#pragma unroll
    for (int j = 0; j < 4; ++j) {
        unsigned long long h = hist[tb + j];
        vex[j] = (double)(h & 0xFFFFFFFFFFFFull) * INV_FIXSCALE;
        vcnt[j] = (unsigned)(h >> 48);
        segtot += vex[j];
    }
    double isuf = segtot;                       // inclusive suffix within wave
#pragma unroll
    for (int d = 1; d < 64; d <<= 1) {
        double u = __shfl_down(isuf, d);
        if (lane + d < 64) isuf += u;
    }
    if (lane == 0) wsum[wv] = isuf;             // wave total
    __syncthreads();
    double wexcl = 0.0;
    for (int w = wv + 1; w < 16; ++w) wexcl += wsum[w];

    double run = cexcl + wexcl + (isuf - segtot);   // S strictly after my 4 buckets
    double local = 0.0;
#pragma unroll
    for (int j = 3; j >= 0; --j) {
        run += vex[j];
        if (vcnt[j]) local += (double)vcnt[j] * log(run);
    }

    // block reduce local
#pragma unroll
    for (int d = 32; d > 0; d >>= 1) {
        double u = __shfl_down(local, d);
        if (lane + d < 64) local += u;
    }
    if (lane == 0) wsumA[wv] = local;
    __syncthreads();
    if (t == 0) {
        double s = 0.0;
        for (int w = 0; w < 16; ++w) s += wsumA[w];
        unsafeAtomicAdd(&scal[1], s);
        __threadfence();
        unsigned tk = atomicAdd(done, 1u);
        if (tk == NBIN - 1) {                   // last block: finalize
            double ld = unsafeAtomicAdd(&scal[1], 0.0);   // device-scope atomic read
            double loss = ld - scal[0];
            if (loss < 0.0) loss = 0.0;
            out[0] = (float)sqrt(loss / (double)n);
        }
    }
}

// ================= fallback path (small ws): R1 pipeline =================
__global__ void k_accum(const float* __restrict__ x, const float* __restrict__ tgt,
                        float* __restrict__ bexp, float* __restrict__ bev,
                        double* __restrict__ evx_out, int ngroups) {
    double local = 0.0;
    const int nt = gridDim.x * blockDim.x;
    const int tid = blockIdx.x * blockDim.x + threadIdx.x;
    const float4* x4 = (const float4*)x;
    const float4* t4 = (const float4*)tgt;
    for (int g = tid; g < ngroups; g += nt) {
        float4 xv = x4[g];
        float4 ta = t4[2 * g];
        float4 tb = t4[2 * g + 1];
        float xs[4] = {xv.x, xv.y, xv.z, xv.w};
        float ts[4] = {ta.x, ta.z, tb.x, tb.z};
        float es[4] = {ta.y, ta.w, tb.y, tb.w};
#pragma unroll
        for (int j = 0; j < 4; ++j) {
            int tau = clamp_tau(ts[j]);
            unsafeAtomicAdd(&bexp[tau], __expf(xs[j]));
            if (es[j] != 0.0f) unsafeAtomicAdd(&bev[tau], es[j]);
            local += (double)(es[j] * xs[j]);
        }
    }
    __shared__ double sm[256];
    sm[threadIdx.x] = local;
    __syncthreads();
    for (int s = 128; s > 0; s >>= 1) {
        if (threadIdx.x < s) sm[threadIdx.x] += sm[threadIdx.x + s];
        __syncthreads();
    }
    if (threadIdx.x == 0) atomicAdd(evx_out, sm[0]);
}

__global__ void k_chunksum(const float* __restrict__ bexp, double* __restrict__ bintot) {
    const int b = blockIdx.x;
    double local = 0.0;
    for (int i = b * BINW + (int)threadIdx.x; i < (b + 1) * BINW; i += (int)blockDim.x)
        local += (double)bexp[i];
    __shared__ double sm[256];
    sm[threadIdx.x] = local;
    __syncthreads();
    for (int s = 128; s > 0; s >>= 1) {
        if (threadIdx.x < s) sm[threadIdx.x] += sm[threadIdx.x + s];
        __syncthreads();
    }
    if (threadIdx.x == 0) bintot[b] = sm[0];
}

__global__ __launch_bounds__(256) void k_scanbins(const double* __restrict__ bintot,
                                                  double* __restrict__ cexcl) {
    __shared__ double sm[256];
    const int t = threadIdx.x;
    sm[t] = (t < NBIN) ? bintot[t] : 0.0;
    __syncthreads();
    for (int d = 1; d < 256; d <<= 1) {
        double v = (t + d < 256) ? sm[t + d] : 0.0;
        __syncthreads();
        sm[t] += v;
        __syncthreads();
    }
    double e = (t + 1 < 256) ? sm[t + 1] : 0.0;
    __syncthreads();
    cexcl[t] = e;
}

__global__ __launch_bounds__(256) void k_logdot_g(const float* __restrict__ bexp,
                                                  const float* __restrict__ bev,
                                                  const double* __restrict__ cexcl,
                                                  double* __restrict__ logdot) {
    const int b = blockIdx.x;
    const int t = threadIdx.x;
    const float4* e4 = (const float4*)(bexp + b * BINW + t * 16);
    const float4* v4 = (const float4*)(bev + b * BINW + t * 16);
    float ve[16], vv[16];
#pragma unroll
    for (int q = 0; q < 4; ++q) {
        float4 a = e4[q], bb = v4[q];
        ve[4 * q] = a.x; ve[4 * q + 1] = a.y; ve[4 * q + 2] = a.z; ve[4 * q + 3] = a.w;
        vv[4 * q] = bb.x; vv[4 * q + 1] = bb.y; vv[4 * q + 2] = bb.z; vv[4 * q + 3] = bb.w;
    }
    double segtot = 0.0;
#pragma unroll
    for (int j = 0; j < 16; ++j) segtot += (double)ve[j];
    __shared__ double sm[256];
    sm[t] = segtot;
    __syncthreads();
    for (int d = 1; d < 256; d <<= 1) {
        double v = (t + d < 256) ? sm[t + d] : 0.0;
        __syncthreads();
        sm[t] += v;
        __syncthreads();
    }
    double excl = (t < 255) ? sm[t + 1] : 0.0;
    double run = cexcl[b] + excl;
    double local = 0.0;
#pragma unroll
    for (int j = 15; j >= 0; --j) {
        run += (double)ve[j];
        if (vv[j] > 0.0f) local += (double)vv[j] * log(run);
    }
    __syncthreads();
    sm[t] = local;
    __syncthreads();
    for (int s = 128; s > 0; s >>= 1) {
        if (t < s) sm[t] += sm[t + s];
        __syncthreads();
    }
    if (t == 0) atomicAdd(logdot, sm[0]);
}

__global__ void k_final(const double* __restrict__ scal, float* __restrict__ out, int n) {
    if (threadIdx.x == 0 && blockIdx.x == 0) {
        double loss = scal[1] - scal[0];
        if (loss < 0.0) loss = 0.0;
        out[0] = (float)sqrt(loss / (double)n);
    }
}

extern "C" void kernel_launch(void* const* d_in, const int* in_sizes, int n_in,
                              void* d_out, int out_size, void* d_ws, size_t ws_size,
                              hipStream_t stream) {
    const float* x = (const float*)d_in[0];
    const float* tgt = (const float*)d_in[1];
    float* out = (float*)d_out;
    int n = in_sizes[0];
    char* ws = (char*)d_ws;

    const size_t ntiles = (size_t)(n + TILE - 1) / TILE;
    const size_t off_pay = (size_t)OFF_LPTAB + ntiles * 512;        // 64B-aligned
    const size_t need2 = off_pay + ntiles * (size_t)TILE * 4;

    if (ws_size >= need2 && n >= 4) {
        double* scal = (double*)(ws + OFF_SCAL);
        unsigned* done = (unsigned*)(ws + OFF_DONE);
        double* bintot = (double*)(ws + OFF_BINTOT);
        unsigned short* lptab = (unsigned short*)(ws + OFF_LPTAB);
        unsigned* payload = (unsigned*)(ws + off_pay);
        hipMemsetAsync(ws, 0, MEMSET_BYTES, stream);
        k_scat2<<<(int)ntiles, NTHR, 0, stream>>>(x, tgt, lptab, payload, bintot, scal, n);
        k_gather<<<NBIN, 1024, 0, stream>>>(payload, lptab, bintot, scal, done, out, n,
                                            (int)ntiles);
    } else if (ws_size >= NEED_MIN) {
        double* scal = (double*)(ws + OFF_SCAL);
        float* bexp = (float*)(ws + FB_BEXP);
        float* bev = (float*)(ws + FB_BEV);
        double* bintotF = (double*)(ws + FB_BINTOT);
        double* cexclF = (double*)(ws + FB_CEXCL);
        hipMemsetAsync(ws, 0, NEED_MIN, stream);
        k_accum<<<2048, 256, 0, stream>>>(x, tgt, bexp, bev, scal, n / 4);
        k_chunksum<<<NBIN, 256, 0, stream>>>(bexp, bintotF);
        k_scanbins<<<1, 256, 0, stream>>>(bintotF, cexclF);
        k_logdot_g<<<NBIN, 256, 0, stream>>>(bexp, bev, cexclF, scal + 1);
        k_final<<<1, 1, 0, stream>>>(scal, out, n);
    }
}